// Round 1
// baseline (3999.142 us; speedup 1.0000x reference)
//
#include <hip/hip_runtime.h>
#include <hip/hip_cooperative_groups.h>

namespace cg = cooperative_groups;

#define HID 512
#define G4 2048      // 4*HID
#define NB 32        // batch
#define LSEQ 64
#define VOC 32000
#define EMBD 256

// ---------------------------------------------------------------------------
// Kernel 1: input projection for encoder & decoder (no recurrent dependency)
// xw[m][n] = emb[tok(m)][:] . Wih[n][:] + b[n],  m = t*32 + b
// ---------------------------------------------------------------------------
__global__ __launch_bounds__(256) void input_proj_kernel(
    const int* __restrict__ Xtok, const int* __restrict__ Ytok,
    const float* __restrict__ embX, const float* __restrict__ embY,
    const float* __restrict__ WE, const float* __restrict__ WD,
    const float* __restrict__ bE, const float* __restrict__ bD,
    float* __restrict__ xwE, float* __restrict__ xwD)
{
    __shared__ float Al[32][68];
    __shared__ float Bl[32][68];
    const int tid = threadIdx.x;
    const int phase = blockIdx.z;                 // 0 = encoder, 1 = decoder
    const int* tokens = phase ? Ytok : Xtok;
    const float* emb  = phase ? embY : embX;
    const float* W    = phase ? WD : WE;
    const float* bv   = phase ? bD : bE;
    float* outp       = phase ? xwD : xwE;

    const int m0 = blockIdx.x * 64;
    const int n0 = blockIdx.y * 64;
    const int tm = tid & 15;
    const int tn = tid >> 4;

    float acc[4][4] = {};

    for (int kc = 0; kc < EMBD; kc += 32) {
#pragma unroll
        for (int r = 0; r < 2; ++r) {
            int i = tid + r * 256;                // 0..511
            int am = i >> 3;                      // row within tile
            int kq = i & 7;                       // float4 within k-chunk
            int m = m0 + am;
            int t = m >> 5, b = m & 31;
            int tok;
            if (phase) { int tt = (t == 0) ? 0 : (t - 1); tok = tokens[b * LSEQ + tt]; }
            else       { tok = tokens[b * LSEQ + t]; }
            float4 av = *(const float4*)&emb[(size_t)tok * EMBD + kc + kq * 4];
            Al[kq * 4 + 0][am] = av.x; Al[kq * 4 + 1][am] = av.y;
            Al[kq * 4 + 2][am] = av.z; Al[kq * 4 + 3][am] = av.w;
            float4 wv = *(const float4*)&W[(size_t)(n0 + am) * EMBD + kc + kq * 4];
            Bl[kq * 4 + 0][am] = wv.x; Bl[kq * 4 + 1][am] = wv.y;
            Bl[kq * 4 + 2][am] = wv.z; Bl[kq * 4 + 3][am] = wv.w;
        }
        __syncthreads();
#pragma unroll
        for (int k = 0; k < 32; ++k) {
            float4 a  = *(const float4*)&Al[k][tm * 4];
            float4 b4 = *(const float4*)&Bl[k][tn * 4];
            acc[0][0] += a.x * b4.x; acc[0][1] += a.x * b4.y; acc[0][2] += a.x * b4.z; acc[0][3] += a.x * b4.w;
            acc[1][0] += a.y * b4.x; acc[1][1] += a.y * b4.y; acc[1][2] += a.y * b4.z; acc[1][3] += a.y * b4.w;
            acc[2][0] += a.z * b4.x; acc[2][1] += a.z * b4.y; acc[2][2] += a.z * b4.z; acc[2][3] += a.z * b4.w;
            acc[3][0] += a.w * b4.x; acc[3][1] += a.w * b4.y; acc[3][2] += a.w * b4.z; acc[3][3] += a.w * b4.w;
        }
        __syncthreads();
    }
    float4 bb = *(const float4*)&bv[n0 + tn * 4];
#pragma unroll
    for (int i = 0; i < 4; ++i) {
        float4 o;
        o.x = acc[i][0] + bb.x; o.y = acc[i][1] + bb.y;
        o.z = acc[i][2] + bb.z; o.w = acc[i][3] + bb.w;
        *(float4*)&outp[(size_t)(m0 + tm * 4 + i) * G4 + n0 + tn * 4] = o;
    }
}

// ---------------------------------------------------------------------------
// Kernel 2: cooperative LSTM recurrence (encoder then decoder, 128 steps).
// 128 blocks; block owns 4 h-columns (16 gate rows). WhhT slice + cell state
// live in LDS for the whole kernel. h ping-pongs through global (k-major
// layout ht[512][32]) with one grid.sync per step.
// Wave w handles k-quarter [w*128, w*128+128); lane = (rg=gate, bg=b-pair),
// register tile 4 rows x 2 batch; partial sums reduced through LDS.
// ---------------------------------------------------------------------------
__global__ __launch_bounds__(256) void lstm_coop_kernel(
    const float* __restrict__ xwE, const float* __restrict__ xwD,
    const float* __restrict__ WhhE, const float* __restrict__ WhhD,
    float* __restrict__ ht0, float* __restrict__ ht1,
    float* __restrict__ hs)
{
    __shared__ float WhhT[HID][16];      // 32 KB, [k][local row]
    __shared__ float htl[HID][32];       // 64 KB, [k][b]
    __shared__ float part[4][16][32];    // 8 KB, [kq][local row][b]
    __shared__ float cst[4][32];         // cell state for this block's 4 cols

    cg::grid_group grid = cg::this_grid();
    const int tid = threadIdx.x;
    const int c0 = blockIdx.x * 4;       // this block's first h-column

    if (tid < 128) {
        int j = tid >> 5, b = tid & 31;
        ht0[(c0 + j) * 32 + b] = 0.f;
        cst[j][b] = 0.f;
    }
    grid.sync();                          // all of ht0 zeroed

    const int w = tid >> 6;               // wave = k-quarter
    const int lane = tid & 63;
    const int rg = lane >> 4;              // gate type 0..3 (i,f,g,o)
    const int bg = lane & 15;              // batch pair
    const int k0 = w * 128;

    float* htb[2] = {ht0, ht1};
    int p = 0;

    for (int phase = 0; phase < 2; ++phase) {
        const float* Whh = phase ? WhhD : WhhE;
        const float* xw  = phase ? xwD  : xwE;
        // load transposed Whh slice once per phase
        for (int idx = tid; idx < 16 * 128; idx += 256) {
            int lr = idx >> 7;             // local row 0..15 = gate*4 + col
            int kq = idx & 127;            // float4 index along k
            int grow = (lr >> 2) * HID + c0 + (lr & 3);
            float4 v = *(const float4*)&Whh[(size_t)grow * HID + kq * 4];
            WhhT[kq * 4 + 0][lr] = v.x; WhhT[kq * 4 + 1][lr] = v.y;
            WhhT[kq * 4 + 2][lr] = v.z; WhhT[kq * 4 + 3][lr] = v.w;
        }
        __syncthreads();

        for (int t = 0; t < LSEQ; ++t) {
            // stage h^T into LDS
            const float4* hsrc = (const float4*)htb[p];
            float4* hdst = (float4*)htl;
            for (int q = tid; q < HID * 32 / 4; q += 256)
                hdst[q] = hsrc[q];
            __syncthreads();

            float acc[4][2];
            if (w == 0) {                  // wave 0 seeds with xw (incl. bias)
#pragma unroll
                for (int bj = 0; bj < 2; ++bj) {
                    int b = bg * 2 + bj;
                    float4 v = *(const float4*)&xw[(size_t)(t * 32 + b) * G4 + rg * HID + c0];
                    acc[0][bj] = v.x; acc[1][bj] = v.y; acc[2][bj] = v.z; acc[3][bj] = v.w;
                }
            } else {
#pragma unroll
                for (int ri = 0; ri < 4; ++ri) { acc[ri][0] = 0.f; acc[ri][1] = 0.f; }
            }

#pragma unroll 4
            for (int k = k0; k < k0 + 128; ++k) {
                float4 wv = *(const float4*)&WhhT[k][rg * 4];
                float2 hv = *(const float2*)&htl[k][bg * 2];
                acc[0][0] += wv.x * hv.x; acc[0][1] += wv.x * hv.y;
                acc[1][0] += wv.y * hv.x; acc[1][1] += wv.y * hv.y;
                acc[2][0] += wv.z * hv.x; acc[2][1] += wv.z * hv.y;
                acc[3][0] += wv.w * hv.x; acc[3][1] += wv.w * hv.y;
            }

#pragma unroll
            for (int ri = 0; ri < 4; ++ri) {
                float2 pv; pv.x = acc[ri][0]; pv.y = acc[ri][1];
                *(float2*)&part[w][rg * 4 + ri][bg * 2] = pv;
            }
            __syncthreads();

            if (tid < 128) {               // gate nonlinearity + state update
                int j = tid >> 5, b = tid & 31;
                float gi = part[0][j][b]      + part[1][j][b]      + part[2][j][b]      + part[3][j][b];
                float gf = part[0][4 + j][b]  + part[1][4 + j][b]  + part[2][4 + j][b]  + part[3][4 + j][b];
                float gg = part[0][8 + j][b]  + part[1][8 + j][b]  + part[2][8 + j][b]  + part[3][8 + j][b];
                float go = part[0][12 + j][b] + part[1][12 + j][b] + part[2][12 + j][b] + part[3][12 + j][b];
                float si = 1.f / (1.f + __expf(-gi));
                float sf = 1.f / (1.f + __expf(-gf));
                float so = 1.f / (1.f + __expf(-go));
                float tg = tanhf(gg);
                float c = sf * cst[j][b] + si * tg;
                cst[j][b] = c;
                float h = so * tanhf(c);
                htb[p ^ 1][(c0 + j) * 32 + b] = h;
                if (phase == 1)
                    hs[(size_t)(t * 32 + b) * HID + c0 + j] = h;
            }
            p ^= 1;
            grid.sync();
        }
    }
}

// ---------------------------------------------------------------------------
// Kernel 3: final FC. logits[b][t][v] = hs[t*32+b][:] . fc_W[v][:] + fc_b[v]
// M=2048, N=32000, K=512, fp32 tiled GEMM, 64x64 tile, 4x4 micro-tile.
// ---------------------------------------------------------------------------
__global__ __launch_bounds__(256) void fc_kernel(
    const float* __restrict__ hs, const float* __restrict__ W,
    const float* __restrict__ bias, float* __restrict__ out)
{
    __shared__ float Al[32][68];
    __shared__ float Bl[32][68];
    const int tid = threadIdx.x;
    const int m0 = blockIdx.x * 64;       // m-tiles fast => fc_W tile reused in L2
    const int n0 = blockIdx.y * 64;
    const int tm = tid & 15;
    const int tn = tid >> 4;

    float acc[4][4] = {};

    for (int kc = 0; kc < HID; kc += 32) {
#pragma unroll
        for (int r = 0; r < 2; ++r) {
            int i = tid + r * 256;
            int am = i >> 3;
            int kq = i & 7;
            float4 av = *(const float4*)&hs[(size_t)(m0 + am) * HID + kc + kq * 4];
            Al[kq * 4 + 0][am] = av.x; Al[kq * 4 + 1][am] = av.y;
            Al[kq * 4 + 2][am] = av.z; Al[kq * 4 + 3][am] = av.w;
            float4 wv = *(const float4*)&W[(size_t)(n0 + am) * HID + kc + kq * 4];
            Bl[kq * 4 + 0][am] = wv.x; Bl[kq * 4 + 1][am] = wv.y;
            Bl[kq * 4 + 2][am] = wv.z; Bl[kq * 4 + 3][am] = wv.w;
        }
        __syncthreads();
#pragma unroll
        for (int k = 0; k < 32; ++k) {
            float4 a  = *(const float4*)&Al[k][tm * 4];
            float4 b4 = *(const float4*)&Bl[k][tn * 4];
            acc[0][0] += a.x * b4.x; acc[0][1] += a.x * b4.y; acc[0][2] += a.x * b4.z; acc[0][3] += a.x * b4.w;
            acc[1][0] += a.y * b4.x; acc[1][1] += a.y * b4.y; acc[1][2] += a.y * b4.z; acc[1][3] += a.y * b4.w;
            acc[2][0] += a.z * b4.x; acc[2][1] += a.z * b4.y; acc[2][2] += a.z * b4.z; acc[2][3] += a.z * b4.w;
            acc[3][0] += a.w * b4.x; acc[3][1] += a.w * b4.y; acc[3][2] += a.w * b4.z; acc[3][3] += a.w * b4.w;
        }
        __syncthreads();
    }

    float4 bb = *(const float4*)&bias[n0 + tn * 4];
#pragma unroll
    for (int i = 0; i < 4; ++i) {
        int m = m0 + tm * 4 + i;
        int t = m >> 5, b = m & 31;
        float4 o;
        o.x = acc[i][0] + bb.x; o.y = acc[i][1] + bb.y;
        o.z = acc[i][2] + bb.z; o.w = acc[i][3] + bb.w;
        *(float4*)&out[(size_t)(b * LSEQ + t) * VOC + n0 + tn * 4] = o;
    }
}

// ---------------------------------------------------------------------------
extern "C" void kernel_launch(void* const* d_in, const int* in_sizes, int n_in,
                              void* d_out, int out_size, void* d_ws, size_t ws_size,
                              hipStream_t stream)
{
    const int*   X    = (const int*)d_in[0];
    const int*   y    = (const int*)d_in[1];
    // d_in[2] = teacher_forcing (always 1, unused)
    const float* embX = (const float*)d_in[3];
    const float* WihE = (const float*)d_in[4];
    const float* WhhE = (const float*)d_in[5];
    const float* bE   = (const float*)d_in[6];
    const float* embY = (const float*)d_in[7];
    const float* WihD = (const float*)d_in[8];
    const float* WhhD = (const float*)d_in[9];
    const float* bD   = (const float*)d_in[10];
    const float* fcW  = (const float*)d_in[11];
    const float* fcB  = (const float*)d_in[12];
    float* out = (float*)d_out;

    char* ws = (char*)d_ws;
    const size_t XW_BYTES = (size_t)2048 * 2048 * 4;   // 16 MB each
    float* xwE = (float*)(ws);
    float* xwD = (float*)(ws + XW_BYTES);
    float* ht0 = (float*)(ws + 2 * XW_BYTES);
    float* ht1 = (float*)(ws + 2 * XW_BYTES + 65536);
    float* hs  = (float*)(ws + 2 * XW_BYTES + 2 * 65536);

    input_proj_kernel<<<dim3(32, 32, 2), 256, 0, stream>>>(
        X, y, embX, embY, WihE, WihD, bE, bD, xwE, xwD);

    {
        const float* a0 = xwE; const float* a1 = xwD;
        const float* a2 = WhhE; const float* a3 = WhhD;
        float* a4 = ht0; float* a5 = ht1; float* a6 = hs;
        void* args[] = {&a0, &a1, &a2, &a3, &a4, &a5, &a6};
        hipLaunchCooperativeKernel((const void*)lstm_coop_kernel, dim3(128), dim3(256),
                                   args, 0, stream);
    }

    fc_kernel<<<dim3(32, 500), 256, 0, stream>>>(hs, fcW, fcB, out);
}

// Round 2
// 2187.861 us; speedup vs baseline: 1.8279x; 1.8279x over previous
//
#include <hip/hip_runtime.h>

#define HID 512
#define G4 2048      // 4*HID
#define LSEQ 64
#define VOC 32000
#define EMBD 256
#define NBLK 128     // lstm blocks (one per 4 h-columns)
#define NTHR 512     // lstm threads per block (8 waves, 8-way k-split)
#define HSZ (HID * 32)      // floats per per-step h buffer (64 KB)
#define FLAG_STRIDE 32      // ints; 128B padding to avoid line contention

// ---------------------------------------------------------------------------
// Kernel 1: input projection for encoder & decoder (no recurrent dependency).
// Produces xwT layout: xwT[(t*2048 + g*512 + col)*32 + b]  (coalesced across b
// for the LSTM gate-combine stage). 64x64 tile GEMM + LDS transpose epilogue.
// ---------------------------------------------------------------------------
__global__ __launch_bounds__(256) void input_proj_kernel(
    const int* __restrict__ Xtok, const int* __restrict__ Ytok,
    const float* __restrict__ embX, const float* __restrict__ embY,
    const float* __restrict__ WE, const float* __restrict__ WD,
    const float* __restrict__ bE, const float* __restrict__ bD,
    float* __restrict__ xwE, float* __restrict__ xwD)
{
    __shared__ float Al[32][68];
    __shared__ float Bl[32][68];
    __shared__ float Cl[64][68];          // [n_local][m_local] transpose buffer
    const int tid = threadIdx.x;
    const int phase = blockIdx.z;         // 0 = encoder, 1 = decoder
    const int* tokens = phase ? Ytok : Xtok;
    const float* emb  = phase ? embY : embX;
    const float* W    = phase ? WD : WE;
    const float* bv   = phase ? bD : bE;
    float* outp       = phase ? xwD : xwE;

    const int m0 = blockIdx.x * 64;
    const int n0 = blockIdx.y * 64;
    const int tm = tid & 15;
    const int tn = tid >> 4;

    float acc[4][4] = {};

    for (int kc = 0; kc < EMBD; kc += 32) {
#pragma unroll
        for (int r = 0; r < 2; ++r) {
            int i = tid + r * 256;                // 0..511
            int am = i >> 3;                      // row within tile
            int kq = i & 7;                       // float4 within k-chunk
            int m = m0 + am;
            int t = m >> 5, b = m & 31;
            int tok;
            if (phase) { int tt = (t == 0) ? 0 : (t - 1); tok = tokens[b * LSEQ + tt]; }
            else       { tok = tokens[b * LSEQ + t]; }
            float4 av = *(const float4*)&emb[(size_t)tok * EMBD + kc + kq * 4];
            Al[kq * 4 + 0][am] = av.x; Al[kq * 4 + 1][am] = av.y;
            Al[kq * 4 + 2][am] = av.z; Al[kq * 4 + 3][am] = av.w;
            float4 wv = *(const float4*)&W[(size_t)(n0 + am) * EMBD + kc + kq * 4];
            Bl[kq * 4 + 0][am] = wv.x; Bl[kq * 4 + 1][am] = wv.y;
            Bl[kq * 4 + 2][am] = wv.z; Bl[kq * 4 + 3][am] = wv.w;
        }
        __syncthreads();
#pragma unroll
        for (int k = 0; k < 32; ++k) {
            float4 a  = *(const float4*)&Al[k][tm * 4];
            float4 b4 = *(const float4*)&Bl[k][tn * 4];
            acc[0][0] += a.x * b4.x; acc[0][1] += a.x * b4.y; acc[0][2] += a.x * b4.z; acc[0][3] += a.x * b4.w;
            acc[1][0] += a.y * b4.x; acc[1][1] += a.y * b4.y; acc[1][2] += a.y * b4.z; acc[1][3] += a.y * b4.w;
            acc[2][0] += a.z * b4.x; acc[2][1] += a.z * b4.y; acc[2][2] += a.z * b4.z; acc[2][3] += a.z * b4.w;
            acc[3][0] += a.w * b4.x; acc[3][1] += a.w * b4.y; acc[3][2] += a.w * b4.z; acc[3][3] += a.w * b4.w;
        }
        __syncthreads();
    }

    // bias + stash into Cl[n_local][m_local]
    float4 bb = *(const float4*)&bv[n0 + tn * 4];
#pragma unroll
    for (int r = 0; r < 4; ++r) {
        Cl[tn * 4 + 0][tm * 4 + r] = acc[r][0] + bb.x;
        Cl[tn * 4 + 1][tm * 4 + r] = acc[r][1] + bb.y;
        Cl[tn * 4 + 2][tm * 4 + r] = acc[r][2] + bb.z;
        Cl[tn * 4 + 3][tm * 4 + r] = acc[r][3] + bb.w;
    }
    __syncthreads();

    const int t0 = m0 >> 5;
#pragma unroll
    for (int r = 0; r < 4; ++r) {
        int f = tid + r * 256;        // 0..1023
        int nl = f >> 4;              // 0..63
        int rem = f & 15;
        int tp = rem >> 3;            // 0..1
        int bq = rem & 7;             // b quad
        float4 v = *(const float4*)&Cl[nl][tp * 32 + bq * 4];
        *(float4*)&outp[((size_t)(t0 + tp) * G4 + n0 + nl) * 32 + bq * 4] = v;
    }
}

// ---------------------------------------------------------------------------
// Kernel 2: LSTM recurrence with NO grid barrier. 128 blocks x 512 threads.
// Block bi owns h-columns 4bi..4bi+3 (16 gate rows). Per step s (0..127):
//   - 8 waves, wave w covers k in [64w,64w+64) = slices [16w,16w+16)
//   - per slice: poll flagseq (RELAXED/AGENT, sc1 -> LLC, never stale),
//     load 128 floats (8B/lane, sc1), stage to LDS wave-locally, 4x8 FMA
//   - partial-sum reduce through LDS, 128 threads do gates + c/h update,
//     publish h slice to per-step buffer H[s+1] (sc1 stores),
//     __syncthreads (drains vmcnt), tid0 RELEASE-stores flagseq[bi]=s+1.
// Per-step h buffers: no WAR hazards => zero barriers between blocks.
// ---------------------------------------------------------------------------
__global__ __launch_bounds__(512) void lstm_coop_kernel(
    const float* __restrict__ xwE, const float* __restrict__ xwD,
    const float* __restrict__ WhhE, const float* __restrict__ WhhD,
    float* __restrict__ H, int* __restrict__ flagseq)
{
    __shared__ float WhhT[HID][16];      // 32 KB, [k][local row = gate*4+col]
    __shared__ float htl[HID][32];       // 64 KB, [k][b]
    __shared__ float part[8][16][32];    // 16 KB, [wave][local row][b]
    __shared__ float cst[4][32];         // cell state for this block's 4 cols

    const int tid = threadIdx.x;
    const int bid = blockIdx.x;
    const int c0 = bid * 4;
    const int w = tid >> 6;              // wave 0..7 -> k in [64w, 64w+64)
    const int lane = tid & 63;
    const int rg = lane >> 4;            // gate 0..3
    const int bg = lane & 15;            // batch pair

    if (tid < 128) cst[tid >> 5][tid & 31] = 0.f;   // first read after barrier

    for (int s = 0; s < 2 * LSEQ; ++s) {
        const int phase = s >> 6;
        const int t = s & 63;
        if (t == 0) {
            const float* Whh = phase ? WhhD : WhhE;
            for (int idx = tid; idx < 16 * 128; idx += NTHR) {
                int lr = idx >> 7;       // local row 0..15
                int kq = idx & 127;      // float4 along k
                int grow = (lr >> 2) * HID + c0 + (lr & 3);
                float4 v = *(const float4*)&Whh[(size_t)grow * HID + kq * 4];
                WhhT[kq * 4 + 0][lr] = v.x; WhhT[kq * 4 + 1][lr] = v.y;
                WhhT[kq * 4 + 2][lr] = v.z; WhhT[kq * 4 + 3][lr] = v.w;
            }
            __syncthreads();
        }

        float acc[4][2] = {};
        const float* Hs = H + (size_t)s * HSZ;

        for (int ii = 0; ii < 16; ++ii) {
            // staggered order; own slice (i==bid for wave bid>>4) comes last
            int i = (w << 4) | ((bid + 1 + ii) & 15);
            while (__hip_atomic_load(&flagseq[i * FLAG_STRIDE],
                                     __ATOMIC_RELAXED, __HIP_MEMORY_SCOPE_AGENT) < s)
                __builtin_amdgcn_s_sleep(1);
            asm volatile("" ::: "memory");   // keep data loads after the poll
            unsigned long long dv = __hip_atomic_load(
                (const unsigned long long*)(Hs + i * 128 + lane * 2),
                __ATOMIC_RELAXED, __HIP_MEMORY_SCOPE_AGENT);
            float2 hv2;
            hv2.x = __uint_as_float((unsigned)(dv & 0xffffffffull));
            hv2.y = __uint_as_float((unsigned)(dv >> 32));
            int kk = 4 * i + (lane >> 4);
            int bb2 = (2 * lane) & 31;
            *(float2*)&htl[kk][bb2] = hv2;   // wave-local staging (in-order DS)

            int kbase = 4 * i;
#pragma unroll
            for (int kd = 0; kd < 4; ++kd) {
                int k = kbase + kd;
                float4 wv = *(const float4*)&WhhT[k][rg * 4];
                float2 hv = *(const float2*)&htl[k][bg * 2];
                acc[0][0] += wv.x * hv.x; acc[0][1] += wv.x * hv.y;
                acc[1][0] += wv.y * hv.x; acc[1][1] += wv.y * hv.y;
                acc[2][0] += wv.z * hv.x; acc[2][1] += wv.z * hv.y;
                acc[3][0] += wv.w * hv.x; acc[3][1] += wv.w * hv.y;
            }
        }

#pragma unroll
        for (int ri = 0; ri < 4; ++ri) {
            float2 pv = make_float2(acc[ri][0], acc[ri][1]);
            *(float2*)&part[w][rg * 4 + ri][bg * 2] = pv;
        }
        __syncthreads();

        if (tid < 128) {                  // gates + state update + publish
            int j = tid >> 5, b = tid & 31;
            float gi = 0.f, gf = 0.f, gg = 0.f, go = 0.f;
#pragma unroll
            for (int q = 0; q < 8; ++q) {
                gi += part[q][j][b];      gf += part[q][4 + j][b];
                gg += part[q][8 + j][b];  go += part[q][12 + j][b];
            }
            const float* xw = phase ? xwD : xwE;
            size_t xb = ((size_t)t * G4 + c0 + j) * 32 + b;
            gi += xw[xb];
            gf += xw[xb + 1 * 512 * 32];
            gg += xw[xb + 2 * 512 * 32];
            go += xw[xb + 3 * 512 * 32];
            float si = 1.f / (1.f + __expf(-gi));
            float sf = 1.f / (1.f + __expf(-gf));
            float so = 1.f / (1.f + __expf(-go));
            float tg = tanhf(gg);
            float c = sf * cst[j][b] + si * tg;
            cst[j][b] = c;
            float h = so * tanhf(c);
            __hip_atomic_store(&H[(size_t)(s + 1) * HSZ + (c0 + j) * 32 + b], h,
                               __ATOMIC_RELAXED, __HIP_MEMORY_SCOPE_AGENT);
        }
        __syncthreads();                  // drains vmcnt(0): h stores at LLC
        if (tid == 0)
            __hip_atomic_store(&flagseq[bid * FLAG_STRIDE], s + 1,
                               __ATOMIC_RELEASE, __HIP_MEMORY_SCOPE_AGENT);
    }
}

// ---------------------------------------------------------------------------
// Kernel 3: final FC. A comes straight from the decoder h buffers:
// Hdec[t*HSZ + k*32 + b] (= H[65+t]), m = t*32+b. M=2048,N=32000,K=512.
// ---------------------------------------------------------------------------
__global__ __launch_bounds__(256) void fc_kernel(
    const float* __restrict__ Hdec, const float* __restrict__ W,
    const float* __restrict__ bias, float* __restrict__ out)
{
    __shared__ float Al[32][68];
    __shared__ float Bl[32][68];
    const int tid = threadIdx.x;
    const int m0 = blockIdx.x * 64;
    const int n0 = blockIdx.y * 64;
    const int t0 = m0 >> 5;
    const int tm = tid & 15;
    const int tn = tid >> 4;

    float acc[4][4] = {};

    for (int kc = 0; kc < HID; kc += 32) {
#pragma unroll
        for (int r = 0; r < 2; ++r) {
            int f = tid + r * 256;            // 0..511
            // A tile: [k][m_local], m_local = tp*32 + bq*4..+3
            int tp = f >> 8;                  // 0..1
            int rem = f & 255;
            int k = rem >> 3;                 // 0..31
            int bq = rem & 7;
            float4 av = *(const float4*)&Hdec[(size_t)(t0 + tp) * HSZ + (kc + k) * 32 + bq * 4];
            *(float4*)&Al[k][tp * 32 + bq * 4] = av;
            // B tile (unchanged mapping)
            int am = f >> 3;
            int kq = f & 7;
            float4 wv = *(const float4*)&W[(size_t)(n0 + am) * HID + kc + kq * 4];
            Bl[kq * 4 + 0][am] = wv.x; Bl[kq * 4 + 1][am] = wv.y;
            Bl[kq * 4 + 2][am] = wv.z; Bl[kq * 4 + 3][am] = wv.w;
        }
        __syncthreads();
#pragma unroll
        for (int k = 0; k < 32; ++k) {
            float4 a  = *(const float4*)&Al[k][tm * 4];
            float4 b4 = *(const float4*)&Bl[k][tn * 4];
            acc[0][0] += a.x * b4.x; acc[0][1] += a.x * b4.y; acc[0][2] += a.x * b4.z; acc[0][3] += a.x * b4.w;
            acc[1][0] += a.y * b4.x; acc[1][1] += a.y * b4.y; acc[1][2] += a.y * b4.z; acc[1][3] += a.y * b4.w;
            acc[2][0] += a.z * b4.x; acc[2][1] += a.z * b4.y; acc[2][2] += a.z * b4.z; acc[2][3] += a.z * b4.w;
            acc[3][0] += a.w * b4.x; acc[3][1] += a.w * b4.y; acc[3][2] += a.w * b4.z; acc[3][3] += a.w * b4.w;
        }
        __syncthreads();
    }

    float4 bb = *(const float4*)&bias[n0 + tn * 4];
#pragma unroll
    for (int i = 0; i < 4; ++i) {
        int m = m0 + tm * 4 + i;
        int t = m >> 5, b = m & 31;
        float4 o;
        o.x = acc[i][0] + bb.x; o.y = acc[i][1] + bb.y;
        o.z = acc[i][2] + bb.z; o.w = acc[i][3] + bb.w;
        *(float4*)&out[(size_t)(b * LSEQ + t) * VOC + n0 + tn * 4] = o;
    }
}

// ---------------------------------------------------------------------------
extern "C" void kernel_launch(void* const* d_in, const int* in_sizes, int n_in,
                              void* d_out, int out_size, void* d_ws, size_t ws_size,
                              hipStream_t stream)
{
    const int*   X    = (const int*)d_in[0];
    const int*   y    = (const int*)d_in[1];
    // d_in[2] = teacher_forcing (always 1, unused)
    const float* embX = (const float*)d_in[3];
    const float* WihE = (const float*)d_in[4];
    const float* WhhE = (const float*)d_in[5];
    const float* bE   = (const float*)d_in[6];
    const float* embY = (const float*)d_in[7];
    const float* WihD = (const float*)d_in[8];
    const float* WhhD = (const float*)d_in[9];
    const float* bD   = (const float*)d_in[10];
    const float* fcW  = (const float*)d_in[11];
    const float* fcB  = (const float*)d_in[12];
    float* out = (float*)d_out;

    char* ws = (char*)d_ws;
    const size_t XW_BYTES   = (size_t)2048 * 2048 * 4;       // 16 MB each
    const size_t FLAG_BYTES = (size_t)NBLK * FLAG_STRIDE * 4; // 16 KB
    float* xwE   = (float*)(ws);
    float* xwD   = (float*)(ws + XW_BYTES);
    int*   flags = (int*)  (ws + 2 * XW_BYTES);
    float* H     = (float*)(ws + 2 * XW_BYTES + FLAG_BYTES);  // 129 * 64 KB

    // reset flags + H[0]=0 every launch (deterministic across graph replays)
    hipMemsetAsync(ws + 2 * XW_BYTES, 0, FLAG_BYTES + (size_t)HSZ * 4, stream);

    input_proj_kernel<<<dim3(32, 32, 2), 256, 0, stream>>>(
        X, y, embX, embY, WihE, WihD, bE, bD, xwE, xwD);

    {
        const float* a0 = xwE; const float* a1 = xwD;
        const float* a2 = WhhE; const float* a3 = WhhD;
        float* a4 = H; int* a5 = flags;
        void* args[] = {&a0, &a1, &a2, &a3, &a4, &a5};
        hipLaunchCooperativeKernel((const void*)lstm_coop_kernel, dim3(NBLK), dim3(NTHR),
                                   args, 0, stream);
    }

    fc_kernel<<<dim3(32, 500), 256, 0, stream>>>(H + (size_t)65 * HSZ, fcW, fcB, out);
}

// Round 3
// 1741.915 us; speedup vs baseline: 2.2958x; 1.2560x over previous
//
#include <hip/hip_runtime.h>

#define HID 512
#define G4 2048      // 4*HID
#define LSEQ 64
#define VOC 32000
#define EMBD 256
#define NBLK 128     // lstm blocks (one per 4 h-columns)
#define NTHR 512     // lstm threads per block (8 waves, 8-way k-split)
#define HSZ (HID * 32)      // floats per per-step h buffer (64 KB)
#define FLAG_STRIDE 32      // ints; 128B padding to avoid line contention

// ---------------------------------------------------------------------------
// Kernel 1: input projection for encoder & decoder (no recurrent dependency).
// Produces xwT layout: xwT[(t*2048 + g*512 + col)*32 + b]  (coalesced across b
// for the LSTM gate-combine stage). 64x64 tile GEMM + LDS transpose epilogue.
// ---------------------------------------------------------------------------
__global__ __launch_bounds__(256) void input_proj_kernel(
    const int* __restrict__ Xtok, const int* __restrict__ Ytok,
    const float* __restrict__ embX, const float* __restrict__ embY,
    const float* __restrict__ WE, const float* __restrict__ WD,
    const float* __restrict__ bE, const float* __restrict__ bD,
    float* __restrict__ xwE, float* __restrict__ xwD)
{
    __shared__ float Al[32][68];
    __shared__ float Bl[32][68];
    __shared__ float Cl[64][68];          // [n_local][m_local] transpose buffer
    const int tid = threadIdx.x;
    const int phase = blockIdx.z;         // 0 = encoder, 1 = decoder
    const int* tokens = phase ? Ytok : Xtok;
    const float* emb  = phase ? embY : embX;
    const float* W    = phase ? WD : WE;
    const float* bv   = phase ? bD : bE;
    float* outp       = phase ? xwD : xwE;

    const int m0 = blockIdx.x * 64;
    const int n0 = blockIdx.y * 64;
    const int tm = tid & 15;
    const int tn = tid >> 4;

    float acc[4][4] = {};

    for (int kc = 0; kc < EMBD; kc += 32) {
#pragma unroll
        for (int r = 0; r < 2; ++r) {
            int i = tid + r * 256;                // 0..511
            int am = i >> 3;                      // row within tile
            int kq = i & 7;                       // float4 within k-chunk
            int m = m0 + am;
            int t = m >> 5, b = m & 31;
            int tok;
            if (phase) { int tt = (t == 0) ? 0 : (t - 1); tok = tokens[b * LSEQ + tt]; }
            else       { tok = tokens[b * LSEQ + t]; }
            float4 av = *(const float4*)&emb[(size_t)tok * EMBD + kc + kq * 4];
            Al[kq * 4 + 0][am] = av.x; Al[kq * 4 + 1][am] = av.y;
            Al[kq * 4 + 2][am] = av.z; Al[kq * 4 + 3][am] = av.w;
            float4 wv = *(const float4*)&W[(size_t)(n0 + am) * EMBD + kc + kq * 4];
            Bl[kq * 4 + 0][am] = wv.x; Bl[kq * 4 + 1][am] = wv.y;
            Bl[kq * 4 + 2][am] = wv.z; Bl[kq * 4 + 3][am] = wv.w;
        }
        __syncthreads();
#pragma unroll
        for (int k = 0; k < 32; ++k) {
            float4 a  = *(const float4*)&Al[k][tm * 4];
            float4 b4 = *(const float4*)&Bl[k][tn * 4];
            acc[0][0] += a.x * b4.x; acc[0][1] += a.x * b4.y; acc[0][2] += a.x * b4.z; acc[0][3] += a.x * b4.w;
            acc[1][0] += a.y * b4.x; acc[1][1] += a.y * b4.y; acc[1][2] += a.y * b4.z; acc[1][3] += a.y * b4.w;
            acc[2][0] += a.z * b4.x; acc[2][1] += a.z * b4.y; acc[2][2] += a.z * b4.z; acc[2][3] += a.z * b4.w;
            acc[3][0] += a.w * b4.x; acc[3][1] += a.w * b4.y; acc[3][2] += a.w * b4.z; acc[3][3] += a.w * b4.w;
        }
        __syncthreads();
    }

    // bias + stash into Cl[n_local][m_local]
    float4 bb = *(const float4*)&bv[n0 + tn * 4];
#pragma unroll
    for (int r = 0; r < 4; ++r) {
        Cl[tn * 4 + 0][tm * 4 + r] = acc[r][0] + bb.x;
        Cl[tn * 4 + 1][tm * 4 + r] = acc[r][1] + bb.y;
        Cl[tn * 4 + 2][tm * 4 + r] = acc[r][2] + bb.z;
        Cl[tn * 4 + 3][tm * 4 + r] = acc[r][3] + bb.w;
    }
    __syncthreads();

    const int t0 = m0 >> 5;
#pragma unroll
    for (int r = 0; r < 4; ++r) {
        int f = tid + r * 256;        // 0..1023
        int nl = f >> 4;              // 0..63
        int rem = f & 15;
        int tp = rem >> 3;            // 0..1
        int bq = rem & 7;             // b quad
        float4 v = *(const float4*)&Cl[nl][tp * 32 + bq * 4];
        *(float4*)&outp[((size_t)(t0 + tp) * G4 + n0 + nl) * 32 + bq * 4] = v;
    }
}

// ---------------------------------------------------------------------------
// Kernel 2: LSTM recurrence, no grid barrier, ONE batched exchange per step.
// 128 blocks x 512 threads. Block bi owns h-columns 4bi..4bi+3.
// Per step s: (a) gate threads prefetch xw (h-independent); (b) wave w
// parallel-polls its 16 producer flags (lane l checks flag base+(l&15), exit
// on __all); (c) 16 slice loads issued back-to-back (all in flight); (d) stage
// to wave-local LDS; (e) 64-k FMA; (f) LDS reduce, gates, publish h slice,
// __syncthreads drains vmcnt, tid0 RELEASE-stores flagseq[bi]=s+1.
// Per-step h buffers: monotonic flags, no WAR hazards, no inter-block barrier.
// ---------------------------------------------------------------------------
__global__ __launch_bounds__(512) void lstm_coop_kernel(
    const float* __restrict__ xwE, const float* __restrict__ xwD,
    const float* __restrict__ WhhE, const float* __restrict__ WhhD,
    float* __restrict__ H, int* __restrict__ flagseq)
{
    __shared__ float WhhT[HID][16];      // 32 KB, [k][local row = gate*4+col]
    __shared__ float htl[HID][32];       // 64 KB, [k][b]
    __shared__ float part[8][16][32];    // 16 KB, [wave][local row][b]
    __shared__ float cst[4][32];         // cell state for this block's 4 cols

    const int tid = threadIdx.x;
    const int bid = blockIdx.x;
    const int c0 = bid * 4;
    const int w = tid >> 6;              // wave 0..7 -> k in [64w, 64w+64)
    const int lane = tid & 63;
    const int rg = lane >> 4;            // gate 0..3
    const int bg = lane & 15;            // batch pair
    const int base = w << 4;             // first slice index for this wave

    if (tid < 128) cst[tid >> 5][tid & 31] = 0.f;   // barrier before first read

    for (int s = 0; s < 2 * LSEQ; ++s) {
        const int phase = s >> 6;
        const int t = s & 63;
        if (t == 0) {
            const float* Whh = phase ? WhhD : WhhE;
            for (int idx = tid; idx < 16 * 128; idx += NTHR) {
                int lr = idx >> 7;       // local row 0..15
                int kq = idx & 127;      // float4 along k
                int grow = (lr >> 2) * HID + c0 + (lr & 3);
                float4 v = *(const float4*)&Whh[(size_t)grow * HID + kq * 4];
                WhhT[kq * 4 + 0][lr] = v.x; WhhT[kq * 4 + 1][lr] = v.y;
                WhhT[kq * 4 + 2][lr] = v.z; WhhT[kq * 4 + 3][lr] = v.w;
            }
            __syncthreads();
        }

        // (a) xw prefetch for gate threads — independent of h, overlaps poll+FMA
        float xg0 = 0.f, xg1 = 0.f, xg2 = 0.f, xg3 = 0.f;
        if (tid < 128) {
            int j = tid >> 5, b = tid & 31;
            const float* xw = phase ? xwD : xwE;
            size_t xb = ((size_t)t * G4 + c0 + j) * 32 + b;
            xg0 = xw[xb];
            xg1 = xw[xb + 1 * 512 * 32];
            xg2 = xw[xb + 2 * 512 * 32];
            xg3 = xw[xb + 3 * 512 * 32];
        }

        const float* Hs = H + (size_t)s * HSZ;

        // (b) parallel poll: 16 producer flags checked wave-wide per iteration
        {
            const int fi = base + (lane & 15);
            for (;;) {
                int f = __hip_atomic_load(&flagseq[fi * FLAG_STRIDE],
                                          __ATOMIC_RELAXED, __HIP_MEMORY_SCOPE_AGENT);
                if (__all(f >= s)) break;
                __builtin_amdgcn_s_sleep(1);
            }
        }
        asm volatile("" ::: "memory");   // keep data loads after the poll

        // (c) batched slice loads — 16 x 8B per lane, all in flight
        unsigned long long dv[16];
#pragma unroll
        for (int ii = 0; ii < 16; ++ii)
            dv[ii] = __hip_atomic_load(
                (const unsigned long long*)(Hs + (size_t)(base + ii) * 128 + lane * 2),
                __ATOMIC_RELAXED, __HIP_MEMORY_SCOPE_AGENT);

        // (d) stage to wave-local LDS region (rows 64w..64w+63)
#pragma unroll
        for (int ii = 0; ii < 16; ++ii) {
            int i = base + ii;
            float2 hv2;
            hv2.x = __uint_as_float((unsigned)(dv[ii] & 0xffffffffull));
            hv2.y = __uint_as_float((unsigned)(dv[ii] >> 32));
            *(float2*)&htl[4 * i + (lane >> 4)][(2 * lane) & 31] = hv2;
        }

        // (e) FMA over this wave's k-range
        float acc[4][2] = {};
        const int k0 = w << 6;
#pragma unroll 8
        for (int k = k0; k < k0 + 64; ++k) {
            float4 wv = *(const float4*)&WhhT[k][rg * 4];
            float2 hv = *(const float2*)&htl[k][bg * 2];
            acc[0][0] += wv.x * hv.x; acc[0][1] += wv.x * hv.y;
            acc[1][0] += wv.y * hv.x; acc[1][1] += wv.y * hv.y;
            acc[2][0] += wv.z * hv.x; acc[2][1] += wv.z * hv.y;
            acc[3][0] += wv.w * hv.x; acc[3][1] += wv.w * hv.y;
        }

#pragma unroll
        for (int ri = 0; ri < 4; ++ri) {
            float2 pv = make_float2(acc[ri][0], acc[ri][1]);
            *(float2*)&part[w][rg * 4 + ri][bg * 2] = pv;
        }
        __syncthreads();

        // (f) gates + state update + publish
        if (tid < 128) {
            int j = tid >> 5, b = tid & 31;
            float gi = xg0, gf = xg1, gg = xg2, go = xg3;
#pragma unroll
            for (int q = 0; q < 8; ++q) {
                gi += part[q][j][b];      gf += part[q][4 + j][b];
                gg += part[q][8 + j][b];  go += part[q][12 + j][b];
            }
            float si = 1.f / (1.f + __expf(-gi));
            float sf = 1.f / (1.f + __expf(-gf));
            float so = 1.f / (1.f + __expf(-go));
            float tg = tanhf(gg);
            float c = sf * cst[j][b] + si * tg;
            cst[j][b] = c;
            float h = so * tanhf(c);
            __hip_atomic_store(&H[(size_t)(s + 1) * HSZ + (c0 + j) * 32 + b], h,
                               __ATOMIC_RELAXED, __HIP_MEMORY_SCOPE_AGENT);
        }
        __syncthreads();                  // drains vmcnt(0): h stores at LLC
        if (tid == 0)
            __hip_atomic_store(&flagseq[bid * FLAG_STRIDE], s + 1,
                               __ATOMIC_RELEASE, __HIP_MEMORY_SCOPE_AGENT);
    }
}

// ---------------------------------------------------------------------------
// Kernel 3: final FC. A comes straight from the decoder h buffers:
// Hdec[t*HSZ + k*32 + b] (= H[65+t]), m = t*32+b. M=2048,N=32000,K=512.
// ---------------------------------------------------------------------------
__global__ __launch_bounds__(256) void fc_kernel(
    const float* __restrict__ Hdec, const float* __restrict__ W,
    const float* __restrict__ bias, float* __restrict__ out)
{
    __shared__ float Al[32][68];
    __shared__ float Bl[32][68];
    const int tid = threadIdx.x;
    const int m0 = blockIdx.x * 64;
    const int n0 = blockIdx.y * 64;
    const int t0 = m0 >> 5;
    const int tm = tid & 15;
    const int tn = tid >> 4;

    float acc[4][4] = {};

    for (int kc = 0; kc < HID; kc += 32) {
#pragma unroll
        for (int r = 0; r < 2; ++r) {
            int f = tid + r * 256;            // 0..511
            // A tile: [k][m_local], m_local = tp*32 + bq*4..+3
            int tp = f >> 8;                  // 0..1
            int rem = f & 255;
            int k = rem >> 3;                 // 0..31
            int bq = rem & 7;
            float4 av = *(const float4*)&Hdec[(size_t)(t0 + tp) * HSZ + (kc + k) * 32 + bq * 4];
            *(float4*)&Al[k][tp * 32 + bq * 4] = av;
            // B tile
            int am = f >> 3;
            int kq = f & 7;
            float4 wv = *(const float4*)&W[(size_t)(n0 + am) * HID + kc + kq * 4];
            Bl[kq * 4 + 0][am] = wv.x; Bl[kq * 4 + 1][am] = wv.y;
            Bl[kq * 4 + 2][am] = wv.z; Bl[kq * 4 + 3][am] = wv.w;
        }
        __syncthreads();
#pragma unroll
        for (int k = 0; k < 32; ++k) {
            float4 a  = *(const float4*)&Al[k][tm * 4];
            float4 b4 = *(const float4*)&Bl[k][tn * 4];
            acc[0][0] += a.x * b4.x; acc[0][1] += a.x * b4.y; acc[0][2] += a.x * b4.z; acc[0][3] += a.x * b4.w;
            acc[1][0] += a.y * b4.x; acc[1][1] += a.y * b4.y; acc[1][2] += a.y * b4.z; acc[1][3] += a.y * b4.w;
            acc[2][0] += a.z * b4.x; acc[2][1] += a.z * b4.y; acc[2][2] += a.z * b4.z; acc[2][3] += a.z * b4.w;
            acc[3][0] += a.w * b4.x; acc[3][1] += a.w * b4.y; acc[3][2] += a.w * b4.z; acc[3][3] += a.w * b4.w;
        }
        __syncthreads();
    }

    float4 bb = *(const float4*)&bias[n0 + tn * 4];
#pragma unroll
    for (int i = 0; i < 4; ++i) {
        int m = m0 + tm * 4 + i;
        int t = m >> 5, b = m & 31;
        float4 o;
        o.x = acc[i][0] + bb.x; o.y = acc[i][1] + bb.y;
        o.z = acc[i][2] + bb.z; o.w = acc[i][3] + bb.w;
        *(float4*)&out[(size_t)(b * LSEQ + t) * VOC + n0 + tn * 4] = o;
    }
}

// ---------------------------------------------------------------------------
extern "C" void kernel_launch(void* const* d_in, const int* in_sizes, int n_in,
                              void* d_out, int out_size, void* d_ws, size_t ws_size,
                              hipStream_t stream)
{
    const int*   X    = (const int*)d_in[0];
    const int*   y    = (const int*)d_in[1];
    // d_in[2] = teacher_forcing (always 1, unused)
    const float* embX = (const float*)d_in[3];
    const float* WihE = (const float*)d_in[4];
    const float* WhhE = (const float*)d_in[5];
    const float* bE   = (const float*)d_in[6];
    const float* embY = (const float*)d_in[7];
    const float* WihD = (const float*)d_in[8];
    const float* WhhD = (const float*)d_in[9];
    const float* bD   = (const float*)d_in[10];
    const float* fcW  = (const float*)d_in[11];
    const float* fcB  = (const float*)d_in[12];
    float* out = (float*)d_out;

    char* ws = (char*)d_ws;
    const size_t XW_BYTES   = (size_t)2048 * 2048 * 4;        // 16 MB each
    const size_t FLAG_BYTES = (size_t)NBLK * FLAG_STRIDE * 4; // 16 KB
    float* xwE   = (float*)(ws);
    float* xwD   = (float*)(ws + XW_BYTES);
    int*   flags = (int*)  (ws + 2 * XW_BYTES);
    float* H     = (float*)(ws + 2 * XW_BYTES + FLAG_BYTES);  // 129 * 64 KB

    // reset flags + H[0]=0 every launch (deterministic across graph replays)
    hipMemsetAsync(ws + 2 * XW_BYTES, 0, FLAG_BYTES + (size_t)HSZ * 4, stream);

    input_proj_kernel<<<dim3(32, 32, 2), 256, 0, stream>>>(
        X, y, embX, embY, WihE, WihD, bE, bD, xwE, xwD);

    {
        const float* a0 = xwE; const float* a1 = xwD;
        const float* a2 = WhhE; const float* a3 = WhhD;
        float* a4 = H; int* a5 = flags;
        void* args[] = {&a0, &a1, &a2, &a3, &a4, &a5};
        hipLaunchCooperativeKernel((const void*)lstm_coop_kernel, dim3(NBLK), dim3(NTHR),
                                   args, 0, stream);
    }

    fc_kernel<<<dim3(32, 500), 256, 0, stream>>>(H + (size_t)65 * HSZ, fcW, fcB, out);
}

// Round 4
// 1090.982 us; speedup vs baseline: 3.6656x; 1.5966x over previous
//
#include <hip/hip_runtime.h>

#define HID 512
#define G4 2048      // 4*HID
#define LSEQ 64
#define VOC 32000
#define EMBD 256
#define NBLK 128     // lstm blocks (one per 4 h-columns)
#define NTHR 512     // lstm threads per block (8 waves, 8-way k-split)
#define HSZ2 (HID * 32 * 2)   // floats per per-step {h,tag} buffer (128 KB)

using s16x8 = __attribute__((ext_vector_type(8))) short;   // 8 bf16 (4 VGPR)
using f32x4 = __attribute__((ext_vector_type(4))) float;   // MFMA acc frag

__device__ inline unsigned short f2bf_rn(float x) {
    unsigned u = __float_as_uint(x);
    unsigned r = (u + 0x7fffu + ((u >> 16) & 1u)) >> 16;
    return (unsigned short)r;
}
__device__ inline float bf2f(unsigned short h) {
    return __uint_as_float(((unsigned)h) << 16);
}
__device__ inline void gload_lds16(const void* g, void* l) {
    __builtin_amdgcn_global_load_lds(
        (const __attribute__((address_space(1))) void*)g,
        (__attribute__((address_space(3))) void*)l, 16, 0, 0);
}

// ---------------------------------------------------------------------------
// Kernel 1: input projection (encoder & decoder). Produces xwT layout:
// xwT[(t*2048 + g*512 + col)*32 + b]. 64x64 tile GEMM + LDS transpose.
// ---------------------------------------------------------------------------
__global__ __launch_bounds__(256) void input_proj_kernel(
    const int* __restrict__ Xtok, const int* __restrict__ Ytok,
    const float* __restrict__ embX, const float* __restrict__ embY,
    const float* __restrict__ WE, const float* __restrict__ WD,
    const float* __restrict__ bE, const float* __restrict__ bD,
    float* __restrict__ xwE, float* __restrict__ xwD)
{
    __shared__ float Al[32][68];
    __shared__ float Bl[32][68];
    __shared__ float Cl[64][68];
    const int tid = threadIdx.x;
    const int phase = blockIdx.z;
    const int* tokens = phase ? Ytok : Xtok;
    const float* emb  = phase ? embY : embX;
    const float* W    = phase ? WD : WE;
    const float* bv   = phase ? bD : bE;
    float* outp       = phase ? xwD : xwE;

    const int m0 = blockIdx.x * 64;
    const int n0 = blockIdx.y * 64;
    const int tm = tid & 15;
    const int tn = tid >> 4;

    float acc[4][4] = {};

    for (int kc = 0; kc < EMBD; kc += 32) {
#pragma unroll
        for (int r = 0; r < 2; ++r) {
            int i = tid + r * 256;
            int am = i >> 3;
            int kq = i & 7;
            int m = m0 + am;
            int t = m >> 5, b = m & 31;
            int tok;
            if (phase) { int tt = (t == 0) ? 0 : (t - 1); tok = tokens[b * LSEQ + tt]; }
            else       { tok = tokens[b * LSEQ + t]; }
            float4 av = *(const float4*)&emb[(size_t)tok * EMBD + kc + kq * 4];
            Al[kq * 4 + 0][am] = av.x; Al[kq * 4 + 1][am] = av.y;
            Al[kq * 4 + 2][am] = av.z; Al[kq * 4 + 3][am] = av.w;
            float4 wv = *(const float4*)&W[(size_t)(n0 + am) * EMBD + kc + kq * 4];
            Bl[kq * 4 + 0][am] = wv.x; Bl[kq * 4 + 1][am] = wv.y;
            Bl[kq * 4 + 2][am] = wv.z; Bl[kq * 4 + 3][am] = wv.w;
        }
        __syncthreads();
#pragma unroll
        for (int k = 0; k < 32; ++k) {
            float4 a  = *(const float4*)&Al[k][tm * 4];
            float4 b4 = *(const float4*)&Bl[k][tn * 4];
            acc[0][0] += a.x * b4.x; acc[0][1] += a.x * b4.y; acc[0][2] += a.x * b4.z; acc[0][3] += a.x * b4.w;
            acc[1][0] += a.y * b4.x; acc[1][1] += a.y * b4.y; acc[1][2] += a.y * b4.z; acc[1][3] += a.y * b4.w;
            acc[2][0] += a.z * b4.x; acc[2][1] += a.z * b4.y; acc[2][2] += a.z * b4.z; acc[2][3] += a.z * b4.w;
            acc[3][0] += a.w * b4.x; acc[3][1] += a.w * b4.y; acc[3][2] += a.w * b4.z; acc[3][3] += a.w * b4.w;
        }
        __syncthreads();
    }

    float4 bb = *(const float4*)&bv[n0 + tn * 4];
#pragma unroll
    for (int r = 0; r < 4; ++r) {
        Cl[tn * 4 + 0][tm * 4 + r] = acc[r][0] + bb.x;
        Cl[tn * 4 + 1][tm * 4 + r] = acc[r][1] + bb.y;
        Cl[tn * 4 + 2][tm * 4 + r] = acc[r][2] + bb.z;
        Cl[tn * 4 + 3][tm * 4 + r] = acc[r][3] + bb.w;
    }
    __syncthreads();

    const int t0 = m0 >> 5;
#pragma unroll
    for (int r = 0; r < 4; ++r) {
        int f = tid + r * 256;
        int nl = f >> 4;
        int rem = f & 15;
        int tp = rem >> 3;
        int bq = rem & 7;
        float4 v = *(const float4*)&Cl[nl][tp * 32 + bq * 4];
        *(float4*)&outp[((size_t)(t0 + tp) * G4 + n0 + nl) * 32 + bq * 4] = v;
    }
}

// ---------------------------------------------------------------------------
// Kernel 2: LSTM recurrence — self-publishing {h, tag} 8B pairs, no flags.
// H[s] holds step-s input h as float2 {h, tag=s} (H[0] memset to 0 => tag 0).
// Consumer wave w retry-loads all 32 pairs of its 16 slices (batched, in
// flight), checks tags in-register; on success data is already in registers.
// Producer publishes with ONE relaxed AGENT 8B store (h + tag s+1) — no
// vmcnt drain, no flag, closing barrier is a raw s_barrier.
// ---------------------------------------------------------------------------
__global__ __launch_bounds__(512) void lstm_coop_kernel(
    const float* __restrict__ xwE, const float* __restrict__ xwD,
    const float* __restrict__ WhhE, const float* __restrict__ WhhD,
    float* __restrict__ H)
{
    __shared__ float WhhT[HID][16];      // 32 KB
    __shared__ float htl[HID][32];       // 64 KB
    __shared__ float part[8][16][32];    // 16 KB
    __shared__ float cst[4][32];

    const int tid = threadIdx.x;
    const int bid = blockIdx.x;
    const int c0 = bid * 4;
    const int w = tid >> 6;
    const int lane = tid & 63;
    const int rg = lane >> 4;
    const int bg = lane & 15;
    const int base = w << 4;             // first slice for this wave

    if (tid < 128) cst[tid >> 5][tid & 31] = 0.f;

    for (int s = 0; s < 2 * LSEQ; ++s) {
        const int phase = s >> 6;
        const int t = s & 63;
        if (t == 0) {
            const float* Whh = phase ? WhhD : WhhE;
            for (int idx = tid; idx < 16 * 128; idx += NTHR) {
                int lr = idx >> 7;
                int kq = idx & 127;
                int grow = (lr >> 2) * HID + c0 + (lr & 3);
                float4 v = *(const float4*)&Whh[(size_t)grow * HID + kq * 4];
                WhhT[kq * 4 + 0][lr] = v.x; WhhT[kq * 4 + 1][lr] = v.y;
                WhhT[kq * 4 + 2][lr] = v.z; WhhT[kq * 4 + 3][lr] = v.w;
            }
            __syncthreads();
        }

        // xw prefetch (h-independent, overlaps the poll)
        float xg0 = 0.f, xg1 = 0.f, xg2 = 0.f, xg3 = 0.f;
        if (tid < 128) {
            int j = tid >> 5, b = tid & 31;
            const float* xw = phase ? xwD : xwE;
            size_t xb = ((size_t)t * G4 + c0 + j) * 32 + b;
            xg0 = xw[xb];
            xg1 = xw[xb + 1 * 512 * 32];
            xg2 = xw[xb + 2 * 512 * 32];
            xg3 = xw[xb + 3 * 512 * 32];
        }

        // batched retry-load of 16 slices x 2 {h,tag} pairs per lane
        const float* sp = H + (size_t)s * HSZ2 + lane * 4;
        unsigned long long dva[16], dvb[16];
        for (;;) {
#pragma unroll
            for (int ii = 0; ii < 16; ++ii) {
                const unsigned long long* p =
                    (const unsigned long long*)(sp + (size_t)(base + ii) * 256);
                dva[ii] = __hip_atomic_load(p,     __ATOMIC_RELAXED, __HIP_MEMORY_SCOPE_AGENT);
                dvb[ii] = __hip_atomic_load(p + 1, __ATOMIC_RELAXED, __HIP_MEMORY_SCOPE_AGENT);
            }
            int ok = 1;
#pragma unroll
            for (int ii = 0; ii < 16; ++ii)
                ok &= ((int)(dva[ii] >> 32) == s) & ((int)(dvb[ii] >> 32) == s);
            if (__all(ok)) break;
            __builtin_amdgcn_s_sleep(1);
        }

        // stage to wave-local LDS region
        {
            int e0 = 2 * lane;           // even, 0..126
            int j = e0 >> 5;
            int bcol = e0 & 31;
#pragma unroll
            for (int ii = 0; ii < 16; ++ii) {
                float2 hv2;
                hv2.x = __uint_as_float((unsigned)(dva[ii] & 0xffffffffull));
                hv2.y = __uint_as_float((unsigned)(dvb[ii] & 0xffffffffull));
                *(float2*)&htl[4 * (base + ii) + j][bcol] = hv2;
            }
        }

        // FMA over this wave's k-range
        float acc[4][2] = {};
        const int k0 = w << 6;
#pragma unroll 8
        for (int k = k0; k < k0 + 64; ++k) {
            float4 wv = *(const float4*)&WhhT[k][rg * 4];
            float2 hv = *(const float2*)&htl[k][bg * 2];
            acc[0][0] += wv.x * hv.x; acc[0][1] += wv.x * hv.y;
            acc[1][0] += wv.y * hv.x; acc[1][1] += wv.y * hv.y;
            acc[2][0] += wv.z * hv.x; acc[2][1] += wv.z * hv.y;
            acc[3][0] += wv.w * hv.x; acc[3][1] += wv.w * hv.y;
        }

#pragma unroll
        for (int ri = 0; ri < 4; ++ri) {
            float2 pv = make_float2(acc[ri][0], acc[ri][1]);
            *(float2*)&part[w][rg * 4 + ri][bg * 2] = pv;
        }
        __syncthreads();

        if (tid < 128) {                  // gates + state update + publish
            int j = tid >> 5, b = tid & 31;
            float gi = xg0, gf = xg1, gg = xg2, go = xg3;
#pragma unroll
            for (int q = 0; q < 8; ++q) {
                gi += part[q][j][b];      gf += part[q][4 + j][b];
                gg += part[q][8 + j][b];  go += part[q][12 + j][b];
            }
            float si = 1.f / (1.f + __expf(-gi));
            float sf = 1.f / (1.f + __expf(-gf));
            float so = 1.f / (1.f + __expf(-go));
            float tg = tanhf(gg);
            float c = sf * cst[j][b] + si * tg;
            cst[j][b] = c;
            float h = so * tanhf(c);
            unsigned long long pv =
                ((unsigned long long)(unsigned)(s + 1) << 32) | __float_as_uint(h);
            __hip_atomic_store(
                (unsigned long long*)&H[(size_t)(s + 1) * HSZ2 + (size_t)(c0 * 32 + j * 32 + b) * 2],
                pv, __ATOMIC_RELAXED, __HIP_MEMORY_SCOPE_AGENT);
        }
        asm volatile("" ::: "memory");
        __builtin_amdgcn_s_barrier();     // part WAR only; no vmcnt drain
    }
}

// ---------------------------------------------------------------------------
// Kernel 4a: convert fc_W (f32) -> Bhi/Blo (bf16), row-major [32000][512].
// ---------------------------------------------------------------------------
__global__ __launch_bounds__(256) void convW_kernel(
    const float* __restrict__ W, short* __restrict__ Bhi, short* __restrict__ Blo)
{
    size_t idx = (size_t)blockIdx.x * 256 + threadIdx.x;   // one per 8 elements
    size_t e0 = idx * 8;
    float4 v0 = *(const float4*)&W[e0];
    float4 v1 = *(const float4*)&W[e0 + 4];
    float xs[8] = {v0.x, v0.y, v0.z, v0.w, v1.x, v1.y, v1.z, v1.w};
    s16x8 h8, l8;
#pragma unroll
    for (int j = 0; j < 8; ++j) {
        unsigned short hi = f2bf_rn(xs[j]);
        h8[j] = (short)hi;
        l8[j] = (short)f2bf_rn(xs[j] - bf2f(hi));
    }
    *(s16x8*)&Bhi[e0] = h8;
    *(s16x8*)&Blo[e0] = l8;
}

// ---------------------------------------------------------------------------
// Kernel 4b: convert decoder H ({h,tag} pairs) -> Ahi/Alo bf16 [2048][512].
// m = t*32 + b. H65 = H + 65*HSZ2 (steps 65..128 hold decoder outputs).
// ---------------------------------------------------------------------------
__global__ __launch_bounds__(256) void convA_kernel(
    const float* __restrict__ H65, short* __restrict__ Ahi, short* __restrict__ Alo)
{
    int idx = blockIdx.x * 256 + threadIdx.x;   // 131072 = 2048 m x 64 k8
    int m = idx & 2047;
    int k8 = idx >> 11;
    int t = m >> 5, b = m & 31;
    const float* Hs = H65 + (size_t)t * HSZ2;
    s16x8 h8, l8;
#pragma unroll
    for (int j = 0; j < 8; ++j) {
        int k = k8 * 8 + j;
        float x = Hs[(size_t)(k * 32 + b) * 2];
        unsigned short hi = f2bf_rn(x);
        h8[j] = (short)hi;
        l8[j] = (short)f2bf_rn(x - bf2f(hi));
    }
    *(s16x8*)&Ahi[(size_t)m * 512 + k8 * 8] = h8;
    *(s16x8*)&Alo[(size_t)m * 512 + k8 * 8] = l8;
}

// ---------------------------------------------------------------------------
// Kernel 5: FC via split-bf16 MFMA. C = Ahi*Bhi + Alo*Bhi + Ahi*Blo (+bias).
// m97 structure: 128x128 tile, 4 waves (2x2), K-step 64, global_load_lds(16),
// ds_read_b128 frags, mfma_f32_16x16x32_bf16, 2 barriers per K-step.
// Virtual K = 1536 = 3 segments x 512. Bijective XCD swizzle (4000 = 8*500).
// ---------------------------------------------------------------------------
__global__ __launch_bounds__(256) void fc_mfma_kernel(
    const short* __restrict__ Ahi, const short* __restrict__ Alo,
    const short* __restrict__ Bhi, const short* __restrict__ Blo,
    const float* __restrict__ bias, float* __restrict__ out)
{
    __shared__ short As[128 * 64];       // [m][k] 16 KB
    __shared__ short Bs[128 * 64];       // [n][k] 16 KB

    const int bi = blockIdx.x;
    const int wg = (bi & 7) * 500 + (bi >> 3);    // XCD-contiguous remap
    const int mt = wg & 15, nt = wg >> 4;
    const int m0 = mt * 128, n0 = nt * 128;
    const int tid = threadIdx.x;
    const int w = tid >> 6, lane = tid & 63;
    const int wm = w >> 1, wn = w & 1;            // wave 2x2 -> 64x64 each
    const int srow = (lane >> 3);                 // staging row-in-group 0..7
    const int scol = (lane & 7) * 8;              // staging k offset (shorts)

    f32x4 acc[4][4] = {};

    for (int ks = 0; ks < 24; ++ks) {
        const int seg = ks >> 3;                  // 0: hi*hi 1: lo*hi 2: hi*lo
        const int kco = (ks & 7) * 64;            // k offset within 512
        const short* Asrc = (seg == 1) ? Alo : Ahi;
        const short* Bsrc = (seg == 2) ? Blo : Bhi;
#pragma unroll
        for (int i = 0; i < 4; ++i) {
            int row = w * 32 + i * 8 + srow;
            gload_lds16(&Asrc[(size_t)(m0 + row) * 512 + kco + scol],
                        (void*)&As[w * 2048 + i * 512]);
            gload_lds16(&Bsrc[(size_t)(n0 + row) * 512 + kco + scol],
                        (void*)&Bs[w * 2048 + i * 512]);
        }
        __syncthreads();

#pragma unroll
        for (int kk = 0; kk < 2; ++kk) {
            s16x8 af[4], bf[4];
#pragma unroll
            for (int f = 0; f < 4; ++f) {
                af[f] = *(const s16x8*)&As[(wm * 64 + f * 16 + (lane & 15)) * 64 + kk * 32 + (lane >> 4) * 8];
                bf[f] = *(const s16x8*)&Bs[(wn * 64 + f * 16 + (lane & 15)) * 64 + kk * 32 + (lane >> 4) * 8];
            }
#pragma unroll
            for (int fm = 0; fm < 4; ++fm)
#pragma unroll
                for (int fn = 0; fn < 4; ++fn)
                    acc[fm][fn] = __builtin_amdgcn_mfma_f32_16x16x32_bf16(
                        af[fm], bf[fn], acc[fm][fn], 0, 0, 0);
        }
        __syncthreads();
    }

    float bb[4];
#pragma unroll
    for (int fn = 0; fn < 4; ++fn)
        bb[fn] = bias[n0 + wn * 64 + fn * 16 + (lane & 15)];

#pragma unroll
    for (int fm = 0; fm < 4; ++fm) {
        int mbase = m0 + wm * 64 + fm * 16 + (lane >> 4) * 4;
#pragma unroll
        for (int r = 0; r < 3 + 1; ++r) {
            int m = mbase + r;
            int t = m >> 5, b = m & 31;
            float* orow = out + (size_t)(b * LSEQ + t) * VOC;
#pragma unroll
            for (int fn = 0; fn < 4; ++fn)
                orow[n0 + wn * 64 + fn * 16 + (lane & 15)] = acc[fm][fn][r] + bb[fn];
        }
    }
}

// ---------------------------------------------------------------------------
extern "C" void kernel_launch(void* const* d_in, const int* in_sizes, int n_in,
                              void* d_out, int out_size, void* d_ws, size_t ws_size,
                              hipStream_t stream)
{
    const int*   X    = (const int*)d_in[0];
    const int*   y    = (const int*)d_in[1];
    // d_in[2] = teacher_forcing (always 1, unused)
    const float* embX = (const float*)d_in[3];
    const float* WihE = (const float*)d_in[4];
    const float* WhhE = (const float*)d_in[5];
    const float* bE   = (const float*)d_in[6];
    const float* embY = (const float*)d_in[7];
    const float* WihD = (const float*)d_in[8];
    const float* WhhD = (const float*)d_in[9];
    const float* bD   = (const float*)d_in[10];
    const float* fcW  = (const float*)d_in[11];
    const float* fcB  = (const float*)d_in[12];
    float* out = (float*)d_out;

    char* ws = (char*)d_ws;
    const size_t XW_BYTES = (size_t)2048 * 2048 * 4;          // 16 MB each
    const size_t H_BYTES  = (size_t)129 * HSZ2 * 4;           // 16.9 MB
    const size_t A_BYTES  = (size_t)2048 * 512 * 2;           // 2 MB each
    const size_t B_BYTES  = (size_t)VOC * 512 * 2;            // 32 MB each

    float* xwE = (float*)(ws);
    float* xwD = (float*)(ws + XW_BYTES);
    float* H   = (float*)(ws + 2 * XW_BYTES);
    short* Ahi = (short*)(ws + 2 * XW_BYTES + H_BYTES);
    short* Alo = (short*)(ws + 2 * XW_BYTES + H_BYTES + A_BYTES);
    short* Bhi = (short*)(ws);                                 // aliases xw (dead)
    short* Blo = (short*)(ws + 2 * XW_BYTES + H_BYTES + 2 * A_BYTES);

    // reset all H tags every launch (honest sync across graph replays);
    // H[0] = {h=0, tag=0} is the step-0 input.
    hipMemsetAsync(ws + 2 * XW_BYTES, 0, H_BYTES, stream);

    input_proj_kernel<<<dim3(32, 32, 2), 256, 0, stream>>>(
        X, y, embX, embY, WihE, WihD, bE, bD, xwE, xwD);

    {
        const float* a0 = xwE; const float* a1 = xwD;
        const float* a2 = WhhE; const float* a3 = WhhD;
        float* a4 = H;
        void* args[] = {&a0, &a1, &a2, &a3, &a4};
        hipLaunchCooperativeKernel((const void*)lstm_coop_kernel, dim3(NBLK), dim3(NTHR),
                                   args, 0, stream);
    }

    convA_kernel<<<512, 256, 0, stream>>>(H + (size_t)65 * HSZ2, Ahi, Alo);
    convW_kernel<<<8000, 256, 0, stream>>>(fcW, Bhi, Blo);   // xw region now dead

    fc_mfma_kernel<<<4000, 256, 0, stream>>>(Ahi, Alo, Bhi, Blo, fcB, out);
}